// Round 1
// baseline (337.358 us; speedup 1.0000x reference)
//
#include <hip/hip_runtime.h>

#define NN      131072
#define H       256
#define PPATHS  32768
#define LMAX    16
#define EF      8
#define FF      16
#define TP      32          // paths per block
#define PES     260         // pe LDS stride (floats): 16B-aligned rows, breaks pow2 banks

// Kernel 0: cvec[j] = b1[j] + sum_k src[k]*W1[k][j] + sum_k dst[k]*W1[256+k][j]
// src/dst are constant rows -> fold 512 of 792 K-dims into one 256-float vector.
__global__ void const_kernel(const float* __restrict__ ne,
                             const float* __restrict__ W1,
                             const float* __restrict__ b1,
                             const int* __restrict__ si,
                             const int* __restrict__ di,
                             float* __restrict__ cvec) {
    __shared__ float red[4][H];
    int j  = threadIdx.x;      // 0..255 column
    int kq = threadIdx.y;      // 0..3 k-quarter
    const float* src = ne + (size_t)si[0] * H;
    const float* dst = ne + (size_t)di[0] * H;
    float c = 0.0f;
    for (int k = kq * 128; k < kq * 128 + 128; ++k) {
        float f = (k < H) ? src[k] : dst[k - H];   // uniform branch per kq
        c += f * W1[(size_t)k * H + j];
    }
    red[kq][j] = c;
    __syncthreads();
    if (kq == 0)
        cvec[j] = b1[j] + red[0][j] + red[1][j] + red[2][j] + red[3][j];
}

__global__ __launch_bounds__(256, 4) void main_kernel(
        const float* __restrict__ node_embs,
        const int*   __restrict__ path_nodes,
        const int*   __restrict__ path_lens,
        const float* __restrict__ edge_f,
        const float* __restrict__ scal_f,
        const float* __restrict__ W1,
        const float* __restrict__ W2,
        const float* __restrict__ b2,
        const float* __restrict__ cvec,
        float*       __restrict__ out) {
    __shared__ __align__(16) float pe[TP * PES];   // path_emb tile, later reused as h-partials
    __shared__ float sedge[TP * EF];
    __shared__ float sscal[TP * FF];
    __shared__ int   sidx[TP * LMAX];
    __shared__ int   slen[TP];
    __shared__ float sden[TP];

    const int tid   = threadIdx.x;
    const int pbase = blockIdx.x * TP;

    // --- metadata staging (coalesced) ---
    if (tid < TP) {
        int len   = path_lens[pbase + tid];
        slen[tid] = len;
        sden[tid] = 1.0f / (float)max(len, 1);
    }
    sedge[tid]       = edge_f[(size_t)pbase * EF + tid];             // 32*8 = 256
    sscal[tid]       = scal_f[(size_t)pbase * FF + tid];             // 32*16 = 512
    sscal[256 + tid] = scal_f[(size_t)pbase * FF + 256 + tid];
    sidx[tid]        = path_nodes[(size_t)pbase * LMAX + tid];       // 32*16 = 512
    sidx[256 + tid]  = path_nodes[(size_t)pbase * LMAX + 256 + tid];
    __syncthreads();

    // --- Phase A: gather + mean. One wave per path (round-robin), float4 rows,
    //     2-way l-unroll for two loads in flight. ---
    const int wave = tid >> 6, lane = tid & 63;
    for (int p = wave; p < TP; p += 4) {
        const int len = slen[p];
        float4 a0 = make_float4(0, 0, 0, 0), a1 = make_float4(0, 0, 0, 0);
        int l = 0;
        for (; l + 1 < len; l += 2) {
            int n0 = sidx[p * LMAX + l];
            int n1 = sidx[p * LMAX + l + 1];
            const float4 v0 = ((const float4*)(node_embs + (size_t)n0 * H))[lane];
            const float4 v1 = ((const float4*)(node_embs + (size_t)n1 * H))[lane];
            a0.x += v0.x; a0.y += v0.y; a0.z += v0.z; a0.w += v0.w;
            a1.x += v1.x; a1.y += v1.y; a1.z += v1.z; a1.w += v1.w;
        }
        if (l < len) {
            int n0 = sidx[p * LMAX + l];
            const float4 v0 = ((const float4*)(node_embs + (size_t)n0 * H))[lane];
            a0.x += v0.x; a0.y += v0.y; a0.z += v0.z; a0.w += v0.w;
        }
        const float inv = sden[p];
        float4 r;
        r.x = (a0.x + a1.x) * inv;
        r.y = (a0.y + a1.y) * inv;
        r.z = (a0.z + a1.z) * inv;
        r.w = (a0.w + a1.w) * inv;
        *(float4*)(pe + p * PES + 4 * lane) = r;
    }
    __syncthreads();

    // --- Phase B: h[p][j] = relu(cvec[j] + pe[p]·W1mid[:,j] + edge·W1e[:,j] + scal·W1s[:,j]) ---
    const int j = tid;
    float h[TP];
    {
        const float c0 = cvec[j];
        #pragma unroll
        for (int p = 0; p < TP; ++p) h[p] = c0;
    }

    const float* W1m = W1 + (size_t)(2 * H) * H + j;   // path_emb rows 512..767
    for (int d4 = 0; d4 < H / 4; ++d4) {
        const float w0 = W1m[(size_t)(4 * d4 + 0) * H];
        const float w1 = W1m[(size_t)(4 * d4 + 1) * H];
        const float w2 = W1m[(size_t)(4 * d4 + 2) * H];
        const float w3 = W1m[(size_t)(4 * d4 + 3) * H];
        #pragma unroll
        for (int p = 0; p < TP; ++p) {
            const float4 pv = *(const float4*)(pe + p * PES + 4 * d4);  // LDS broadcast
            h[p] += pv.x * w0 + pv.y * w1 + pv.z * w2 + pv.w * w3;
        }
    }
    {
        const float* W1e = W1 + (size_t)(3 * H) * H + j;  // edge rows 768..775
        #pragma unroll
        for (int e = 0; e < EF; ++e) {
            const float w = W1e[(size_t)e * H];
            #pragma unroll
            for (int p = 0; p < TP; ++p) h[p] += sedge[p * EF + e] * w;
        }
        const float* W1s = W1 + (size_t)(3 * H + EF) * H + j;  // scalar rows 776..791
        #pragma unroll
        for (int f = 0; f < FF; ++f) {
            const float w = W1s[(size_t)f * H];
            #pragma unroll
            for (int p = 0; p < TP; ++p) h[p] += sscal[p * FF + f] * w;
        }
    }

    // relu + W2 column scale
    {
        const float w2j = W2[j];
        #pragma unroll
        for (int p = 0; p < TP; ++p) h[p] = fmaxf(h[p], 0.0f) * w2j;
    }

    __syncthreads();   // pe tile dead; reuse for per-path partials
    #pragma unroll
    for (int p = 0; p < TP; ++p) pe[p * PES + j] = h[p];
    __syncthreads();

    // --- Phase C: q[p] = sum_j + b2; empty paths -> exactly 0 ---
    if (tid < TP) {
        float s = 0.0f;
        for (int jj = 0; jj < H; ++jj) s += pe[tid * PES + jj];  // stride 260 -> 4-way max
        float q = s + b2[0];
        out[pbase + tid] = (slen[tid] > 0) ? q : 0.0f;
    }
}

extern "C" void kernel_launch(void* const* d_in, const int* in_sizes, int n_in,
                              void* d_out, int out_size, void* d_ws, size_t ws_size,
                              hipStream_t stream) {
    const float* node_embs = (const float*)d_in[0];
    const int*   path_nodes = (const int*)d_in[1];
    const int*   path_lens  = (const int*)d_in[2];
    const float* edge_f     = (const float*)d_in[3];
    const float* scal_f     = (const float*)d_in[4];
    const float* W1         = (const float*)d_in[5];
    const float* b1         = (const float*)d_in[6];
    const float* W2         = (const float*)d_in[7];
    const float* b2         = (const float*)d_in[8];
    const int*   si         = (const int*)d_in[9];
    const int*   di         = (const int*)d_in[10];
    float* out  = (float*)d_out;
    float* cvec = (float*)d_ws;   // 256 floats

    hipLaunchKernelGGL(const_kernel, dim3(1), dim3(256, 4), 0, stream,
                       node_embs, W1, b1, si, di, cvec);
    hipLaunchKernelGGL(main_kernel, dim3(PPATHS / TP), dim3(256), 0, stream,
                       node_embs, path_nodes, path_lens, edge_f, scal_f,
                       W1, W2, b2, cvec, out);
}

// Round 2
// 280.120 us; speedup vs baseline: 1.2043x; 1.2043x over previous
//
#include <hip/hip_runtime.h>

#define NN      131072
#define H       256
#define PPATHS  32768
#define LMAX    16
#define EF      8
#define FF      16
#define TP      64          // paths per block
#define FS      296         // feat LDS stride in ushort (592 B rows: 8B/16B aligned, odd/32 bank mix)
#define KTOT    280         // 256 pe + 8 edge + 16 scal

__device__ __forceinline__ unsigned short f2bf(float x) {
    unsigned int u = __float_as_uint(x);
    u += 0x7fffu + ((u >> 16) & 1u);     // round-to-nearest-even
    return (unsigned short)(u >> 16);
}

// cvec[j] = b1[j] + sum_{k<512} f[k]*W1[k][j], f = concat(src,dst). 64 blocks x 4 cols.
__global__ void const_kernel(const float* __restrict__ ne,
                             const float* __restrict__ W1,
                             const float* __restrict__ b1,
                             const int* __restrict__ si,
                             const int* __restrict__ di,
                             float* __restrict__ cvec) {
    __shared__ float red[256];
    const int t  = threadIdx.x;
    const int jl = t & 3, kp = t >> 2;
    const int j  = blockIdx.x * 4 + jl;
    const float* src = ne + (size_t)si[0] * H;
    const float* dst = ne + (size_t)di[0] * H;
    float c = 0.0f;
    #pragma unroll
    for (int i = 0; i < 8; ++i) {
        int k = kp + i * 64;                       // covers 0..511 exactly once
        float f = (k < H) ? src[k] : dst[k - H];
        c += f * W1[(size_t)k * H + j];
    }
    red[t] = c;
    __syncthreads();
    for (int s = 128; s >= 4; s >>= 1) {
        if (t < s) red[t] += red[t + s];
        __syncthreads();
    }
    if (t < 4) cvec[blockIdx.x * 4 + t] = b1[blockIdx.x * 4 + t] + red[t];
}

__global__ __launch_bounds__(256, 3) void main_kernel(
        const float* __restrict__ node_embs,
        const int*   __restrict__ path_nodes,
        const int*   __restrict__ path_lens,
        const float* __restrict__ edge_f,
        const float* __restrict__ scal_f,
        const float* __restrict__ W1,
        const float* __restrict__ W2,
        const float* __restrict__ b2,
        const float* __restrict__ cvec,
        float*       __restrict__ out) {
    // feat[p][k] bf16: k 0..255 = path_emb, 256..263 = edge, 264..279 = scalar
    __shared__ __align__(16) unsigned short feat[TP * FS];     // 37.9 KB
    __shared__ int   sidx[TP * LMAX];                          // 4 KB
    __shared__ int   slen[TP];
    __shared__ float sden[TP];
    __shared__ float qpart[TP * 33];                           // 8.4 KB, stride 33 breaks banks

    const int tid   = threadIdx.x;
    const int pbase = blockIdx.x * TP;

    // --- metadata staging (coalesced) ---
    if (tid < TP) {
        int len   = path_lens[pbase + tid];
        slen[tid] = len;
        sden[tid] = 1.0f / (float)max(len, 1);
    }
    #pragma unroll
    for (int i = 0; i < 4; ++i)                                // 64*16 = 1024 ints
        sidx[tid + 256 * i] = path_nodes[(size_t)pbase * LMAX + tid + 256 * i];

    // edge + scalar features -> feat cols 256..279 (bf16)
    for (int i = tid; i < TP * 32; i += 256) {
        int p = i >> 5, s = i & 31;
        if (s < EF)
            feat[p * FS + H + s] = f2bf(edge_f[(size_t)(pbase + p) * EF + s]);
        else if (s < EF + FF)
            feat[p * FS + H + s] = f2bf(scal_f[(size_t)(pbase + p) * FF + (s - EF)]);
    }
    __syncthreads();

    // --- Phase A: gather + mean, one wave per 16 paths, 4-deep load unroll ---
    const int wave = tid >> 6, lane = tid & 63;
    for (int p = wave * 16; p < wave * 16 + 16; ++p) {
        const int len = slen[p];
        const int* idx = &sidx[p * LMAX];
        float4 a0 = make_float4(0, 0, 0, 0), a1 = make_float4(0, 0, 0, 0);
        float4 a2 = make_float4(0, 0, 0, 0), a3 = make_float4(0, 0, 0, 0);
        int l = 0;
        for (; l + 3 < len; l += 4) {
            const float4 v0 = ((const float4*)(node_embs + (size_t)idx[l]     * H))[lane];
            const float4 v1 = ((const float4*)(node_embs + (size_t)idx[l + 1] * H))[lane];
            const float4 v2 = ((const float4*)(node_embs + (size_t)idx[l + 2] * H))[lane];
            const float4 v3 = ((const float4*)(node_embs + (size_t)idx[l + 3] * H))[lane];
            a0.x += v0.x; a0.y += v0.y; a0.z += v0.z; a0.w += v0.w;
            a1.x += v1.x; a1.y += v1.y; a1.z += v1.z; a1.w += v1.w;
            a2.x += v2.x; a2.y += v2.y; a2.z += v2.z; a2.w += v2.w;
            a3.x += v3.x; a3.y += v3.y; a3.z += v3.z; a3.w += v3.w;
        }
        for (; l < len; ++l) {
            const float4 v0 = ((const float4*)(node_embs + (size_t)idx[l] * H))[lane];
            a0.x += v0.x; a0.y += v0.y; a0.z += v0.z; a0.w += v0.w;
        }
        const float inv = sden[p];
        ushort4 r;
        r.x = f2bf((a0.x + a1.x + a2.x + a3.x) * inv);
        r.y = f2bf((a0.y + a1.y + a2.y + a3.y) * inv);
        r.z = f2bf((a0.z + a1.z + a2.z + a3.z) * inv);
        r.w = f2bf((a0.w + a1.w + a2.w + a3.w) * inv);
        *(ushort4*)&feat[p * FS + 4 * lane] = r;               // 8B aligned: (296p+4l)*2
    }
    __syncthreads();

    // --- Phase B: register-tiled GEMM. thread = 8 paths x 8 cols ---
    const int pg = tid >> 5, jg = tid & 31;
    const int p0 = pg * 8, j0 = jg * 8;

    float h[8][8];
    {
        const float4 c0 = *(const float4*)(cvec + j0);
        const float4 c1 = *(const float4*)(cvec + j0 + 4);
        #pragma unroll
        for (int pi = 0; pi < 8; ++pi) {
            h[pi][0] = c0.x; h[pi][1] = c0.y; h[pi][2] = c0.z; h[pi][3] = c0.w;
            h[pi][4] = c1.x; h[pi][5] = c1.y; h[pi][6] = c1.z; h[pi][7] = c1.w;
        }
    }

    const float* Wk = W1 + (size_t)(2 * H) * H + j0;           // rows 512.., col j0
    for (int k = 0; k < KTOT; k += 4) {
        float w[4][8];
        #pragma unroll
        for (int ki = 0; ki < 4; ++ki) {
            const float4 wa = *(const float4*)(Wk + (size_t)(k + ki) * H);
            const float4 wb = *(const float4*)(Wk + (size_t)(k + ki) * H + 4);
            w[ki][0] = wa.x; w[ki][1] = wa.y; w[ki][2] = wa.z; w[ki][3] = wa.w;
            w[ki][4] = wb.x; w[ki][5] = wb.y; w[ki][6] = wb.z; w[ki][7] = wb.w;
        }
        #pragma unroll
        for (int pi = 0; pi < 8; ++pi) {
            const uint2 pr = *(const uint2*)&feat[(p0 + pi) * FS + k];  // 4 bf16, 2-way bcast
            float f[4];
            f[0] = __uint_as_float(pr.x << 16);
            f[1] = __uint_as_float(pr.x & 0xffff0000u);
            f[2] = __uint_as_float(pr.y << 16);
            f[3] = __uint_as_float(pr.y & 0xffff0000u);
            #pragma unroll
            for (int ki = 0; ki < 4; ++ki)
                #pragma unroll
                for (int ji = 0; ji < 8; ++ji)
                    h[pi][ji] = fmaf(f[ki], w[ki][ji], h[pi][ji]);
        }
    }

    // --- epilogue: relu, *W2, per-thread j-reduction ---
    {
        float w2v[8];
        const float4 wa = *(const float4*)(W2 + j0);
        const float4 wb = *(const float4*)(W2 + j0 + 4);
        w2v[0] = wa.x; w2v[1] = wa.y; w2v[2] = wa.z; w2v[3] = wa.w;
        w2v[4] = wb.x; w2v[5] = wb.y; w2v[6] = wb.z; w2v[7] = wb.w;
        #pragma unroll
        for (int pi = 0; pi < 8; ++pi) {
            float s = 0.0f;
            #pragma unroll
            for (int ji = 0; ji < 8; ++ji)
                s += fmaxf(h[pi][ji], 0.0f) * w2v[ji];
            qpart[(p0 + pi) * 33 + jg] = s;
        }
    }
    __syncthreads();

    // --- Phase C: reduce 32 partials per path ---
    if (tid < TP) {
        float s = 0.0f;
        #pragma unroll
        for (int jj = 0; jj < 32; ++jj) s += qpart[tid * 33 + jj];
        out[pbase + tid] = (slen[tid] > 0) ? (s + b2[0]) : 0.0f;
    }
}

extern "C" void kernel_launch(void* const* d_in, const int* in_sizes, int n_in,
                              void* d_out, int out_size, void* d_ws, size_t ws_size,
                              hipStream_t stream) {
    const float* node_embs  = (const float*)d_in[0];
    const int*   path_nodes = (const int*)d_in[1];
    const int*   path_lens  = (const int*)d_in[2];
    const float* edge_f     = (const float*)d_in[3];
    const float* scal_f     = (const float*)d_in[4];
    const float* W1         = (const float*)d_in[5];
    const float* b1         = (const float*)d_in[6];
    const float* W2         = (const float*)d_in[7];
    const float* b2         = (const float*)d_in[8];
    const int*   si         = (const int*)d_in[9];
    const int*   di         = (const int*)d_in[10];
    float* out  = (float*)d_out;
    float* cvec = (float*)d_ws;   // 256 floats

    hipLaunchKernelGGL(const_kernel, dim3(64), dim3(256), 0, stream,
                       node_embs, W1, b1, si, di, cvec);
    hipLaunchKernelGGL(main_kernel, dim3(PPATHS / TP), dim3(256), 0, stream,
                       node_embs, path_nodes, path_lens, edge_f, scal_f,
                       W1, W2, b2, cvec, out);
}

// Round 3
// 237.147 us; speedup vs baseline: 1.4226x; 1.1812x over previous
//
#include <hip/hip_runtime.h>

#define NN      131072
#define H       256
#define PPATHS  32768
#define LMAX    16
#define EF      8
#define FF      16
#define KP      288        // padded K: 256 pe + 8 edge + 16 scal + 8 zero

typedef short v8s __attribute__((ext_vector_type(8)));
typedef float v4f __attribute__((ext_vector_type(4)));

__device__ __forceinline__ unsigned short f2bf(float x) {
    unsigned int u = __float_as_uint(x);
    u += 0x7fffu + ((u >> 16) & 1u);     // round-to-nearest-even
    return (unsigned short)(u >> 16);
}

// cvec[j] = b1[j] + sum_{k<512} concat(src,dst)[k] * W1[k][j]
__global__ void const_kernel(const float* __restrict__ ne,
                             const float* __restrict__ W1,
                             const float* __restrict__ b1,
                             const int* __restrict__ si,
                             const int* __restrict__ di,
                             float* __restrict__ cvec) {
    __shared__ float red[256];
    const int t  = threadIdx.x;
    const int jl = t & 3, kp = t >> 2;
    const int j  = blockIdx.x * 4 + jl;
    const float* src = ne + (size_t)si[0] * H;
    const float* dst = ne + (size_t)di[0] * H;
    float c = 0.0f;
    #pragma unroll
    for (int i = 0; i < 8; ++i) {
        int k = kp + i * 64;
        float f = (k < H) ? src[k] : dst[k - H];
        c += f * W1[(size_t)k * H + j];
    }
    red[t] = c;
    __syncthreads();
    for (int s = 128; s >= 4; s >>= 1) {
        if (t < s) red[t] += red[t + s];
        __syncthreads();
    }
    if (t < 4) cvec[blockIdx.x * 4 + t] = b1[blockIdx.x * 4 + t] + red[t];
}

// W1T[n][k] = bf16(W1[orig(k)][n]); k>=280 -> 0.  B-fragment-friendly layout.
__global__ void conv_kernel(const float* __restrict__ W1,
                            unsigned short* __restrict__ W1T) {
    const int k = blockIdx.x;        // 0..287
    const int n = threadIdx.x;       // 0..255 (coalesced read)
    float v = 0.0f;
    if (k < 256)      v = W1[(size_t)(512 + k) * H + n];          // path_emb rows
    else if (k < 280) v = W1[(size_t)(768 + (k - 256)) * H + n];  // edge+scal rows
    W1T[(size_t)n * KP + k] = f2bf(v);
}

// One wave per path: gather+mean -> feat[p][0..255] bf16; cols 256..287 = edge/scal/zeros.
__global__ __launch_bounds__(256) void gather_kernel(
        const float* __restrict__ node_embs,
        const int*   __restrict__ path_nodes,
        const int*   __restrict__ path_lens,
        const float* __restrict__ edge_f,
        const float* __restrict__ scal_f,
        unsigned short* __restrict__ feat) {
    const int wave = threadIdx.x >> 6, lane = threadIdx.x & 63;
    const int p    = blockIdx.x * 4 + wave;
    const int len  = path_lens[p];
    const int iv   = path_nodes[(size_t)p * LMAX + (lane & 15)];

    float4 a0 = make_float4(0, 0, 0, 0), a1 = make_float4(0, 0, 0, 0);
    float4 a2 = make_float4(0, 0, 0, 0), a3 = make_float4(0, 0, 0, 0);
    int l = 0;
    for (; l + 3 < len; l += 4) {
        const int n0 = __shfl(iv, l);
        const int n1 = __shfl(iv, l + 1);
        const int n2 = __shfl(iv, l + 2);
        const int n3 = __shfl(iv, l + 3);
        const float4 v0 = ((const float4*)(node_embs + (size_t)n0 * H))[lane];
        const float4 v1 = ((const float4*)(node_embs + (size_t)n1 * H))[lane];
        const float4 v2 = ((const float4*)(node_embs + (size_t)n2 * H))[lane];
        const float4 v3 = ((const float4*)(node_embs + (size_t)n3 * H))[lane];
        a0.x += v0.x; a0.y += v0.y; a0.z += v0.z; a0.w += v0.w;
        a1.x += v1.x; a1.y += v1.y; a1.z += v1.z; a1.w += v1.w;
        a2.x += v2.x; a2.y += v2.y; a2.z += v2.z; a2.w += v2.w;
        a3.x += v3.x; a3.y += v3.y; a3.z += v3.z; a3.w += v3.w;
    }
    for (; l < len; ++l) {
        const int n0 = __shfl(iv, l);
        const float4 v0 = ((const float4*)(node_embs + (size_t)n0 * H))[lane];
        a0.x += v0.x; a0.y += v0.y; a0.z += v0.z; a0.w += v0.w;
    }
    const float inv = 1.0f / (float)max(len, 1);
    ushort4 r;
    r.x = f2bf((a0.x + a1.x + a2.x + a3.x) * inv);
    r.y = f2bf((a0.y + a1.y + a2.y + a3.y) * inv);
    r.z = f2bf((a0.z + a1.z + a2.z + a3.z) * inv);
    r.w = f2bf((a0.w + a1.w + a2.w + a3.w) * inv);
    *(ushort4*)(feat + (size_t)p * KP + 4 * lane) = r;   // 8B aligned

    if (lane < 32) {                                     // cols 256..287
        float v = 0.0f;
        if (lane < EF)            v = edge_f[(size_t)p * EF + lane];
        else if (lane < EF + FF)  v = scal_f[(size_t)p * FF + (lane - EF)];
        feat[(size_t)p * KP + H + lane] = f2bf(v);
    }
}

// Block = 64 paths x 256 cols; wave w owns n in [64w, 64w+64). No LDS in K-loop.
__global__ __launch_bounds__(256) void gemm_kernel(
        const unsigned short* __restrict__ feat,
        const unsigned short* __restrict__ W1T,
        const float* __restrict__ cvec,
        const float* __restrict__ W2,
        const float* __restrict__ b2,
        const int*   __restrict__ path_lens,
        float*       __restrict__ out) {
    __shared__ float qpart[64][5];
    const int wave = threadIdx.x >> 6, lane = threadIdx.x & 63;
    const int pb   = blockIdx.x * 64;
    const int col  = lane & 15, quad = lane >> 4;
    const int n0   = wave * 64;

    v4f acc[4][4];
    float w2v[4];
    #pragma unroll
    for (int nt = 0; nt < 4; ++nt) {
        const float cv = cvec[n0 + nt * 16 + col];
        w2v[nt] = W2[n0 + nt * 16 + col];
        #pragma unroll
        for (int mt = 0; mt < 4; ++mt)
            acc[mt][nt] = (v4f){cv, cv, cv, cv};
    }

    // A-frag: lane holds feat[pb + mt*16 + col][k0 + quad*8 + j], j=0..7 (16B contig)
    // B-frag: lane holds W1T [n0 + nt*16 + col][k0 + quad*8 + j]       (16B contig)
    const unsigned short* Abase = feat + (size_t)(pb + col) * KP + quad * 8;
    const unsigned short* Bbase = W1T + (size_t)(n0 + col) * KP + quad * 8;

    for (int k0 = 0; k0 < KP; k0 += 32) {
        v8s a[4], b[4];
        #pragma unroll
        for (int mt = 0; mt < 4; ++mt)
            a[mt] = *(const v8s*)(Abase + (size_t)(mt * 16) * KP + k0);
        #pragma unroll
        for (int nt = 0; nt < 4; ++nt)
            b[nt] = *(const v8s*)(Bbase + (size_t)(nt * 16) * KP + k0);
        #pragma unroll
        for (int mt = 0; mt < 4; ++mt)
            #pragma unroll
            for (int nt = 0; nt < 4; ++nt)
                acc[mt][nt] = __builtin_amdgcn_mfma_f32_16x16x32_bf16(
                                  a[mt], b[nt], acc[mt][nt], 0, 0, 0);
    }

    // Epilogue: relu * W2, reduce over this wave's 64 cols, stash per-wave partial.
    // C/D layout: col = lane&15, row = quad*4 + reg  [m89-verified]
    #pragma unroll
    for (int mt = 0; mt < 4; ++mt) {
        float s[4];
        #pragma unroll
        for (int r = 0; r < 4; ++r) {
            float v = 0.0f;
            #pragma unroll
            for (int nt = 0; nt < 4; ++nt)
                v += fmaxf(acc[mt][nt][r], 0.0f) * w2v[nt];
            s[r] = v;
        }
        #pragma unroll
        for (int off = 1; off < 16; off <<= 1) {
            #pragma unroll
            for (int r = 0; r < 4; ++r)
                s[r] += __shfl_xor(s[r], off);
        }
        if (col == 0) {
            #pragma unroll
            for (int r = 0; r < 4; ++r)
                qpart[mt * 16 + quad * 4 + r][wave] = s[r];
        }
    }
    __syncthreads();

    if (threadIdx.x < 64) {
        const int t = threadIdx.x;
        const float q = qpart[t][0] + qpart[t][1] + qpart[t][2] + qpart[t][3] + b2[0];
        out[pb + t] = (path_lens[pb + t] > 0) ? q : 0.0f;
    }
}

extern "C" void kernel_launch(void* const* d_in, const int* in_sizes, int n_in,
                              void* d_out, int out_size, void* d_ws, size_t ws_size,
                              hipStream_t stream) {
    const float* node_embs  = (const float*)d_in[0];
    const int*   path_nodes = (const int*)d_in[1];
    const int*   path_lens  = (const int*)d_in[2];
    const float* edge_f     = (const float*)d_in[3];
    const float* scal_f     = (const float*)d_in[4];
    const float* W1         = (const float*)d_in[5];
    const float* b1         = (const float*)d_in[6];
    const float* W2         = (const float*)d_in[7];
    const float* b2         = (const float*)d_in[8];
    const int*   si         = (const int*)d_in[9];
    const int*   di         = (const int*)d_in[10];
    float* out = (float*)d_out;

    // workspace layout (16B-aligned): cvec | W1T | feat  (~19.02 MB total)
    float*          cvec = (float*)d_ws;                               // 1 KB
    unsigned short* W1T  = (unsigned short*)((char*)d_ws + 1024);      // 147456 B
    unsigned short* feat = (unsigned short*)((char*)d_ws + 148480);    // 18874368 B

    hipLaunchKernelGGL(const_kernel, dim3(64), dim3(256), 0, stream,
                       node_embs, W1, b1, si, di, cvec);
    hipLaunchKernelGGL(conv_kernel, dim3(KP), dim3(256), 0, stream, W1, W1T);
    hipLaunchKernelGGL(gather_kernel, dim3(PPATHS / 4), dim3(256), 0, stream,
                       node_embs, path_nodes, path_lens, edge_f, scal_f, feat);
    hipLaunchKernelGGL(gemm_kernel, dim3(PPATHS / 64), dim3(256), 0, stream,
                       feat, W1T, cvec, W2, b2, path_lens, out);
}

// Round 4
// 234.076 us; speedup vs baseline: 1.4412x; 1.0131x over previous
//
#include <hip/hip_runtime.h>

#define NN      131072
#define H       256
#define PPATHS  32768
#define LMAX    16
#define EF      8
#define FF      16
#define KP      288        // padded K: 256 pe + 8 edge + 16 scal + 8 zero
#define GB      (PPATHS/4) // gather blocks (4 paths/block, 1 wave/path)

typedef short v8s __attribute__((ext_vector_type(8)));
typedef float v4f __attribute__((ext_vector_type(4)));

__device__ __forceinline__ unsigned short f2bf(float x) {
    unsigned int u = __float_as_uint(x);
    u += 0x7fffu + ((u >> 16) & 1u);     // round-to-nearest-even
    return (unsigned short)(u >> 16);
}

// Fused: blocks [0,GB) gather+mean -> feat; blocks [GB,GB+288) W1->W1T bf16
// transpose; blocks [GB+288,GB+352) cvec (src/dst rows folded + b1).
// Prep blocks overlap the gather instead of serializing in front of it.
__global__ __launch_bounds__(256) void gather_prep_kernel(
        const float* __restrict__ node_embs,
        const int*   __restrict__ path_nodes,
        const int*   __restrict__ path_lens,
        const float* __restrict__ edge_f,
        const float* __restrict__ scal_f,
        const float* __restrict__ W1,
        const float* __restrict__ b1,
        const int*   __restrict__ si,
        const int*   __restrict__ di,
        unsigned short* __restrict__ feat,
        unsigned short* __restrict__ W1T,
        float*       __restrict__ cvec) {
    __shared__ float red[256];
    const int bid = blockIdx.x;

    if (bid >= GB) {
        const int b = bid - GB;
        if (b < KP) {
            // W1T[n][k] = bf16(W1[orig(k)][n]); k>=280 -> 0
            const int k = b, n = threadIdx.x;
            float v = 0.0f;
            if (k < 256)      v = W1[(size_t)(512 + k) * H + n];
            else if (k < 280) v = W1[(size_t)(768 + (k - 256)) * H + n];
            W1T[(size_t)n * KP + k] = f2bf(v);
        } else {
            // cvec[j] = b1[j] + sum_{k<512} concat(src,dst)[k] * W1[k][j]
            const int jb = b - KP;             // 0..63
            const int t  = threadIdx.x;
            const int jl = t & 3, kp = t >> 2;
            const int j  = jb * 4 + jl;
            const float* src = node_embs + (size_t)si[0] * H;
            const float* dst = node_embs + (size_t)di[0] * H;
            float c = 0.0f;
            #pragma unroll
            for (int i = 0; i < 8; ++i) {
                int k = kp + i * 64;
                float f = (k < H) ? src[k] : dst[k - H];
                c += f * W1[(size_t)k * H + j];
            }
            red[t] = c;
            __syncthreads();
            for (int s = 128; s >= 4; s >>= 1) {
                if (t < s) red[t] += red[t + s];
                __syncthreads();
            }
            if (t < 4) cvec[jb * 4 + t] = b1[jb * 4 + t] + red[t];
        }
        return;
    }

    // --- gather+mean, one wave per path ---
    const int wave = threadIdx.x >> 6, lane = threadIdx.x & 63;
    const int p    = bid * 4 + wave;
    const int len  = path_lens[p];
    const int iv   = path_nodes[(size_t)p * LMAX + (lane & 15)];

    float4 a0 = make_float4(0, 0, 0, 0), a1 = make_float4(0, 0, 0, 0);
    float4 a2 = make_float4(0, 0, 0, 0), a3 = make_float4(0, 0, 0, 0);
    int l = 0;
    for (; l + 3 < len; l += 4) {
        const int n0 = __shfl(iv, l);
        const int n1 = __shfl(iv, l + 1);
        const int n2 = __shfl(iv, l + 2);
        const int n3 = __shfl(iv, l + 3);
        const float4 v0 = ((const float4*)(node_embs + (size_t)n0 * H))[lane];
        const float4 v1 = ((const float4*)(node_embs + (size_t)n1 * H))[lane];
        const float4 v2 = ((const float4*)(node_embs + (size_t)n2 * H))[lane];
        const float4 v3 = ((const float4*)(node_embs + (size_t)n3 * H))[lane];
        a0.x += v0.x; a0.y += v0.y; a0.z += v0.z; a0.w += v0.w;
        a1.x += v1.x; a1.y += v1.y; a1.z += v1.z; a1.w += v1.w;
        a2.x += v2.x; a2.y += v2.y; a2.z += v2.z; a2.w += v2.w;
        a3.x += v3.x; a3.y += v3.y; a3.z += v3.z; a3.w += v3.w;
    }
    for (; l < len; ++l) {
        const int n0 = __shfl(iv, l);
        const float4 v0 = ((const float4*)(node_embs + (size_t)n0 * H))[lane];
        a0.x += v0.x; a0.y += v0.y; a0.z += v0.z; a0.w += v0.w;
    }
    const float inv = 1.0f / (float)max(len, 1);
    ushort4 r;
    r.x = f2bf((a0.x + a1.x + a2.x + a3.x) * inv);
    r.y = f2bf((a0.y + a1.y + a2.y + a3.y) * inv);
    r.z = f2bf((a0.z + a1.z + a2.z + a3.z) * inv);
    r.w = f2bf((a0.w + a1.w + a2.w + a3.w) * inv);
    *(ushort4*)(feat + (size_t)p * KP + 4 * lane) = r;   // 8B aligned

    if (lane < 32) {                                     // cols 256..287 (incl. zero pad)
        float v = 0.0f;
        if (lane < EF)            v = edge_f[(size_t)p * EF + lane];
        else if (lane < EF + FF)  v = scal_f[(size_t)p * FF + (lane - EF)];
        feat[(size_t)p * KP + H + lane] = f2bf(v);
    }
}

// Block = 32 paths x 256 cols (grid 1024 -> 4 blocks/CU); wave w owns n in
// [64w, 64w+64). No LDS, no barriers in the K-loop.
__global__ __launch_bounds__(256) void gemm_kernel(
        const unsigned short* __restrict__ feat,
        const unsigned short* __restrict__ W1T,
        const float* __restrict__ cvec,
        const float* __restrict__ W2,
        const float* __restrict__ b2,
        const int*   __restrict__ path_lens,
        float*       __restrict__ out) {
    __shared__ float qpart[32][5];
    const int wave = threadIdx.x >> 6, lane = threadIdx.x & 63;
    const int pb   = blockIdx.x * 32;
    const int col  = lane & 15, quad = lane >> 4;
    const int n0   = wave * 64;

    v4f acc[2][4];
    float w2v[4];
    #pragma unroll
    for (int nt = 0; nt < 4; ++nt) {
        const float cv = cvec[n0 + nt * 16 + col];
        w2v[nt] = W2[n0 + nt * 16 + col];
        #pragma unroll
        for (int mt = 0; mt < 2; ++mt)
            acc[mt][nt] = (v4f){cv, cv, cv, cv};
    }

    // A-frag: lane holds feat[pb + mt*16 + col][k0 + quad*8 + j], j=0..7 (16B contig)
    // B-frag: lane holds W1T [n0 + nt*16 + col][k0 + quad*8 + j]       (16B contig)
    const unsigned short* Abase = feat + (size_t)(pb + col) * KP + quad * 8;
    const unsigned short* Bbase = W1T + (size_t)(n0 + col) * KP + quad * 8;

    for (int k0 = 0; k0 < KP; k0 += 32) {
        v8s a[2], b[4];
        #pragma unroll
        for (int mt = 0; mt < 2; ++mt)
            a[mt] = *(const v8s*)(Abase + (size_t)(mt * 16) * KP + k0);
        #pragma unroll
        for (int nt = 0; nt < 4; ++nt)
            b[nt] = *(const v8s*)(Bbase + (size_t)(nt * 16) * KP + k0);
        #pragma unroll
        for (int mt = 0; mt < 2; ++mt)
            #pragma unroll
            for (int nt = 0; nt < 4; ++nt)
                acc[mt][nt] = __builtin_amdgcn_mfma_f32_16x16x32_bf16(
                                  a[mt], b[nt], acc[mt][nt], 0, 0, 0);
    }

    // Epilogue: relu * W2, reduce over this wave's 64 cols, stash per-wave partial.
    // C/D layout: col = lane&15, row = quad*4 + reg  [m89-verified]
    #pragma unroll
    for (int mt = 0; mt < 2; ++mt) {
        float s[4];
        #pragma unroll
        for (int r = 0; r < 4; ++r) {
            float v = 0.0f;
            #pragma unroll
            for (int nt = 0; nt < 4; ++nt)
                v += fmaxf(acc[mt][nt][r], 0.0f) * w2v[nt];
            s[r] = v;
        }
        #pragma unroll
        for (int off = 1; off < 16; off <<= 1) {
            #pragma unroll
            for (int r = 0; r < 4; ++r)
                s[r] += __shfl_xor(s[r], off);
        }
        if (col == 0) {
            #pragma unroll
            for (int r = 0; r < 4; ++r)
                qpart[mt * 16 + quad * 4 + r][wave] = s[r];
        }
    }
    __syncthreads();

    if (threadIdx.x < 32) {
        const int t = threadIdx.x;
        const float q = qpart[t][0] + qpart[t][1] + qpart[t][2] + qpart[t][3] + b2[0];
        out[pb + t] = (path_lens[pb + t] > 0) ? q : 0.0f;
    }
}

extern "C" void kernel_launch(void* const* d_in, const int* in_sizes, int n_in,
                              void* d_out, int out_size, void* d_ws, size_t ws_size,
                              hipStream_t stream) {
    const float* node_embs  = (const float*)d_in[0];
    const int*   path_nodes = (const int*)d_in[1];
    const int*   path_lens  = (const int*)d_in[2];
    const float* edge_f     = (const float*)d_in[3];
    const float* scal_f     = (const float*)d_in[4];
    const float* W1         = (const float*)d_in[5];
    const float* b1         = (const float*)d_in[6];
    const float* W2         = (const float*)d_in[7];
    const float* b2         = (const float*)d_in[8];
    const int*   si         = (const int*)d_in[9];
    const int*   di         = (const int*)d_in[10];
    float* out = (float*)d_out;

    // workspace layout (16B-aligned): cvec | W1T | feat  (~19.02 MB total)
    float*          cvec = (float*)d_ws;                               // 1 KB
    unsigned short* W1T  = (unsigned short*)((char*)d_ws + 1024);      // 147456 B
    unsigned short* feat = (unsigned short*)((char*)d_ws + 148480);    // 18874368 B

    hipLaunchKernelGGL(gather_prep_kernel, dim3(GB + KP + 64), dim3(256), 0, stream,
                       node_embs, path_nodes, path_lens, edge_f, scal_f,
                       W1, b1, si, di, feat, W1T, cvec);
    hipLaunchKernelGGL(gemm_kernel, dim3(PPATHS / 32), dim3(256), 0, stream,
                       feat, W1T, cvec, W2, b2, path_lens, out);
}

// Round 5
// 230.106 us; speedup vs baseline: 1.4661x; 1.0173x over previous
//
#include <hip/hip_runtime.h>

#define NN      131072
#define H       256
#define PPATHS  32768
#define LMAX    16
#define EF      8
#define FF      16
#define KP      288        // padded K: 256 pe + 8 edge + 16 scal + 8 zero
#define TPB     32         // paths per block (fused kernel)
#define FS      296        // feat LDS row stride in ushorts (592 B: 16B-aligned)

typedef short v8s __attribute__((ext_vector_type(8)));
typedef float v4f __attribute__((ext_vector_type(4)));

__device__ __forceinline__ unsigned short f2bf(float x) {
    unsigned int u = __float_as_uint(x);
    u += 0x7fffu + ((u >> 16) & 1u);     // round-to-nearest-even
    return (unsigned short)(u >> 16);
}

// blocks [0,288): W1T[n][k] = bf16(W1[orig(k)][n]) (k>=280 -> 0)
// blocks [288,352): cvec[j] = b1[j] + sum_{k<512} concat(src,dst)[k]*W1[k][j]
__global__ __launch_bounds__(256) void prep_kernel(
        const float* __restrict__ node_embs,
        const float* __restrict__ W1,
        const float* __restrict__ b1,
        const int*   __restrict__ si,
        const int*   __restrict__ di,
        unsigned short* __restrict__ W1T,
        float*       __restrict__ cvec) {
    __shared__ float red[256];
    const int b = blockIdx.x;
    if (b < KP) {
        const int k = b, n = threadIdx.x;
        float v = 0.0f;
        if (k < 256)      v = W1[(size_t)(512 + k) * H + n];
        else if (k < 280) v = W1[(size_t)(768 + (k - 256)) * H + n];
        W1T[(size_t)n * KP + k] = f2bf(v);
    } else {
        const int jb = b - KP;             // 0..63
        const int t  = threadIdx.x;
        const int jl = t & 3, kp = t >> 2;
        const int j  = jb * 4 + jl;
        const float* src = node_embs + (size_t)si[0] * H;
        const float* dst = node_embs + (size_t)di[0] * H;
        float c = 0.0f;
        #pragma unroll
        for (int i = 0; i < 8; ++i) {
            int k = kp + i * 64;
            float f = (k < H) ? src[k] : dst[k - H];
            c += f * W1[(size_t)k * H + j];
        }
        red[t] = c;
        __syncthreads();
        for (int s = 128; s >= 4; s >>= 1) {
            if (t < s) red[t] += red[t + s];
            __syncthreads();
        }
        if (t < 4) cvec[jb * 4 + t] = b1[jb * 4 + t] + red[t];
    }
}

// Fused: block = 32 paths. Phase A: 4 waves gather 8 paths each -> LDS bf16
// feat tile. Phase B: MFMA GEMM, A-frags from LDS, B-frags from L2-resident
// W1T; fused relu/W2/reduce epilogue. No feat global round-trip.
__global__ __launch_bounds__(256, 4) void fused_kernel(
        const float* __restrict__ node_embs,
        const int*   __restrict__ path_nodes,
        const int*   __restrict__ path_lens,
        const float* __restrict__ edge_f,
        const float* __restrict__ scal_f,
        const unsigned short* __restrict__ W1T,
        const float* __restrict__ cvec,
        const float* __restrict__ W2,
        const float* __restrict__ b2,
        float*       __restrict__ out) {
    __shared__ __align__(16) unsigned short feat[TPB * FS];   // 18.94 KB
    __shared__ float qpart[TPB][5];

    const int tid  = threadIdx.x;
    const int wave = tid >> 6, lane = tid & 63;
    const int pb   = blockIdx.x * TPB;

    // cols 256..287: edge, scalar, zero pad (issued first so loads fly early)
    for (int i = tid; i < TPB * 32; i += 256) {
        const int p = i >> 5, s = i & 31;
        float v = 0.0f;
        if (s < EF)           v = edge_f[(size_t)(pb + p) * EF + s];
        else if (s < EF + FF) v = scal_f[(size_t)(pb + p) * FF + (s - EF)];
        feat[p * FS + H + s] = f2bf(v);
    }

    // Phase A: gather + mean, wave w handles paths [8w, 8w+8)
    for (int pi = 0; pi < 8; ++pi) {
        const int p   = wave * 8 + pi;
        const int gp  = pb + p;
        const int len = path_lens[gp];
        const int iv  = path_nodes[(size_t)gp * LMAX + (lane & 15)];

        float4 a0 = make_float4(0, 0, 0, 0), a1 = make_float4(0, 0, 0, 0);
        float4 a2 = make_float4(0, 0, 0, 0), a3 = make_float4(0, 0, 0, 0);
        int l = 0;
        for (; l + 3 < len; l += 4) {
            const int n0 = __shfl(iv, l);
            const int n1 = __shfl(iv, l + 1);
            const int n2 = __shfl(iv, l + 2);
            const int n3 = __shfl(iv, l + 3);
            const float4 v0 = ((const float4*)(node_embs + (size_t)n0 * H))[lane];
            const float4 v1 = ((const float4*)(node_embs + (size_t)n1 * H))[lane];
            const float4 v2 = ((const float4*)(node_embs + (size_t)n2 * H))[lane];
            const float4 v3 = ((const float4*)(node_embs + (size_t)n3 * H))[lane];
            a0.x += v0.x; a0.y += v0.y; a0.z += v0.z; a0.w += v0.w;
            a1.x += v1.x; a1.y += v1.y; a1.z += v1.z; a1.w += v1.w;
            a2.x += v2.x; a2.y += v2.y; a2.z += v2.z; a2.w += v2.w;
            a3.x += v3.x; a3.y += v3.y; a3.z += v3.z; a3.w += v3.w;
        }
        for (; l < len; ++l) {
            const int n0 = __shfl(iv, l);
            const float4 v0 = ((const float4*)(node_embs + (size_t)n0 * H))[lane];
            a0.x += v0.x; a0.y += v0.y; a0.z += v0.z; a0.w += v0.w;
        }
        const float inv = 1.0f / (float)max(len, 1);
        ushort4 r;
        r.x = f2bf((a0.x + a1.x + a2.x + a3.x) * inv);
        r.y = f2bf((a0.y + a1.y + a2.y + a3.y) * inv);
        r.z = f2bf((a0.z + a1.z + a2.z + a3.z) * inv);
        r.w = f2bf((a0.w + a1.w + a2.w + a3.w) * inv);
        *(ushort4*)&feat[p * FS + 4 * lane] = r;     // 8B aligned
    }
    __syncthreads();

    // Phase B: MFMA GEMM. wave w owns cols n in [64w, 64w+64).
    const int col = lane & 15, quad = lane >> 4;
    const int n0  = wave * 64;

    v4f acc[2][4];
    float w2v[4];
    #pragma unroll
    for (int nt = 0; nt < 4; ++nt) {
        const float cv = cvec[n0 + nt * 16 + col];
        w2v[nt] = W2[n0 + nt * 16 + col];
        #pragma unroll
        for (int mt = 0; mt < 2; ++mt)
            acc[mt][nt] = (v4f){cv, cv, cv, cv};
    }

    // A-frag: lane holds feat[mt*16 + col][k0 + quad*8 + j]  (LDS, 16B contig)
    // B-frag: lane holds W1T [n0 + nt*16 + col][k0 + quad*8 + j]
    const unsigned short* Alds  = feat + col * FS + quad * 8;
    const unsigned short* Bbase = W1T + (size_t)(n0 + col) * KP + quad * 8;

    for (int k0 = 0; k0 < KP; k0 += 32) {
        v8s a[2], b[4];
        #pragma unroll
        for (int mt = 0; mt < 2; ++mt)
            a[mt] = *(const v8s*)(Alds + mt * 16 * FS + k0);
        #pragma unroll
        for (int nt = 0; nt < 4; ++nt)
            b[nt] = *(const v8s*)(Bbase + (size_t)(nt * 16) * KP + k0);
        #pragma unroll
        for (int mt = 0; mt < 2; ++mt)
            #pragma unroll
            for (int nt = 0; nt < 4; ++nt)
                acc[mt][nt] = __builtin_amdgcn_mfma_f32_16x16x32_bf16(
                                  a[mt], b[nt], acc[mt][nt], 0, 0, 0);
    }

    // Epilogue: relu * W2, reduce this wave's 64 cols; C/D: col=lane&15, row=quad*4+r
    #pragma unroll
    for (int mt = 0; mt < 2; ++mt) {
        float s[4];
        #pragma unroll
        for (int r = 0; r < 4; ++r) {
            float v = 0.0f;
            #pragma unroll
            for (int nt = 0; nt < 4; ++nt)
                v += fmaxf(acc[mt][nt][r], 0.0f) * w2v[nt];
            s[r] = v;
        }
        #pragma unroll
        for (int off = 1; off < 16; off <<= 1) {
            #pragma unroll
            for (int r = 0; r < 4; ++r)
                s[r] += __shfl_xor(s[r], off);
        }
        if (col == 0) {
            #pragma unroll
            for (int r = 0; r < 4; ++r)
                qpart[mt * 16 + quad * 4 + r][wave] = s[r];
        }
    }
    __syncthreads();

    if (tid < TPB) {
        const float q = qpart[tid][0] + qpart[tid][1] + qpart[tid][2] + qpart[tid][3] + b2[0];
        out[pb + tid] = (path_lens[pb + tid] > 0) ? q : 0.0f;
    }
}

extern "C" void kernel_launch(void* const* d_in, const int* in_sizes, int n_in,
                              void* d_out, int out_size, void* d_ws, size_t ws_size,
                              hipStream_t stream) {
    const float* node_embs  = (const float*)d_in[0];
    const int*   path_nodes = (const int*)d_in[1];
    const int*   path_lens  = (const int*)d_in[2];
    const float* edge_f     = (const float*)d_in[3];
    const float* scal_f     = (const float*)d_in[4];
    const float* W1         = (const float*)d_in[5];
    const float* b1         = (const float*)d_in[6];
    const float* W2         = (const float*)d_in[7];
    const float* b2         = (const float*)d_in[8];
    const int*   si         = (const int*)d_in[9];
    const int*   di         = (const int*)d_in[10];
    float* out = (float*)d_out;

    // workspace: cvec (1 KB) | W1T (147456 B)
    float*          cvec = (float*)d_ws;
    unsigned short* W1T  = (unsigned short*)((char*)d_ws + 1024);

    hipLaunchKernelGGL(prep_kernel, dim3(KP + 64), dim3(256), 0, stream,
                       node_embs, W1, b1, si, di, W1T, cvec);
    hipLaunchKernelGGL(fused_kernel, dim3(PPATHS / TPB), dim3(256), 0, stream,
                       node_embs, path_nodes, path_lens, edge_f, scal_f,
                       W1T, cvec, W2, b2, out);
}